// Round 1
// baseline (4653.838 us; speedup 1.0000x reference)
//
#include <hip/hip_runtime.h>

#define NB 4
#define NSEQ 2048
#define DIMW 512
#define HEADS 8
#define DHEAD 64
#define SCALEF 0.125f
#define PS 2052  // padded score-row stride (floats)

// ---------------- fp32 GEMM: C[M,512] = A[M,512] @ W[512,512] (+bias) ------
// grid (M/64, 512/64), block 256. 64x64 tile, 4x4 microtile, BK=16.
__global__ __launch_bounds__(256) void gemm512_f32(
    const float* __restrict__ A, const float* __restrict__ W,
    float* __restrict__ C, const float* __restrict__ bias) {
  __shared__ float As[16][68];
  __shared__ float Ws[16][68];
  const int t = threadIdx.x;
  const int bm = blockIdx.x * 64;
  const int bn = blockIdx.y * 64;
  const int ty = t >> 4, tx = t & 15;
  const int lr = t >> 2, lk = (t & 3) << 2;   // A-tile load: 64 rows x 16 k
  const int wk = t >> 4, wn = (t & 15) << 2;  // W-tile load: 16 k x 64 n
  float acc[4][4] = {};
  for (int k0 = 0; k0 < DIMW; k0 += 16) {
    float4 a = *(const float4*)&A[(size_t)(bm + lr) * DIMW + k0 + lk];
    As[lk + 0][lr] = a.x;
    As[lk + 1][lr] = a.y;
    As[lk + 2][lr] = a.z;
    As[lk + 3][lr] = a.w;
    *(float4*)&Ws[wk][wn] = *(const float4*)&W[(size_t)(k0 + wk) * DIMW + bn + wn];
    __syncthreads();
#pragma unroll
    for (int k = 0; k < 16; ++k) {
      float4 av = *(float4*)&As[k][ty << 2];
      float4 wv = *(float4*)&Ws[k][tx << 2];
      float ar[4] = {av.x, av.y, av.z, av.w};
      float wr[4] = {wv.x, wv.y, wv.z, wv.w};
#pragma unroll
      for (int i = 0; i < 4; ++i)
#pragma unroll
        for (int j = 0; j < 4; ++j) acc[i][j] = fmaf(ar[i], wr[j], acc[i][j]);
    }
    __syncthreads();
  }
  const int col = bn + (tx << 2);
  float4 bv = {0.f, 0.f, 0.f, 0.f};
  if (bias) bv = *(const float4*)&bias[col];
#pragma unroll
  for (int i = 0; i < 4; ++i) {
    const int row = bm + (ty << 2) + i;
    float4 o = {acc[i][0] + bv.x, acc[i][1] + bv.y,
                acc[i][2] + bv.z, acc[i][3] + bv.w};
    *(float4*)&C[(size_t)row * DIMW + col] = o;
  }
}

// ---------------- attention: one block = (bh, 16 query rows) ---------------
// grid (128 qtiles, 32 bh), block 256. Full 2048-wide score rows in LDS.
__global__ __launch_bounds__(256) void attn_f32(
    const float* __restrict__ Q, const float* __restrict__ K,
    const float* __restrict__ V, const float* __restrict__ Qm,
    const float* __restrict__ Km, float* __restrict__ attnO,
    float* __restrict__ O1) {
  __shared__ float Qs[16][68], Qms[16][68], Ks[16][68], Kms[16][68];
  __shared__ float P[16 * PS];
  __shared__ float red[256];
  __shared__ float rowmax[16], rowinv[16];
  const int t = threadIdx.x;
  const int qt = blockIdx.x;  // 0..127
  const int bh = blockIdx.y;  // 0..31
  const int b = bh >> 3, h = bh & 7;
  const int hoff = h * DHEAD;
  const int lr = t >> 4;         // 0..15
  const int d4 = (t & 15) << 2;  // 0,4,..,60
  const int r = t >> 4, jj = t & 15;

  {  // load Q / Qm tiles (16 rows x 64)
    size_t g = (size_t)(b * NSEQ + qt * 16 + lr) * DIMW + hoff + d4;
    *(float4*)&Qs[lr][d4] = *(const float4*)&Q[g];
    *(float4*)&Qms[lr][d4] = *(const float4*)&Qm[g];
  }

  // ---- scores: sim = (q.k + qm.km) * SCALE, staged K tiles of 16 rows ----
  for (int jt = 0; jt < NSEQ; jt += 16) {
    __syncthreads();
    {
      size_t g = (size_t)(b * NSEQ + jt + lr) * DIMW + hoff + d4;
      *(float4*)&Ks[lr][d4] = *(const float4*)&K[g];
      *(float4*)&Kms[lr][d4] = *(const float4*)&Km[g];
    }
    __syncthreads();
    float s = 0.f;
#pragma unroll
    for (int c = 0; c < DHEAD; c += 4) {
      float4 q = *(float4*)&Qs[r][c];
      float4 k = *(float4*)&Ks[jj][c];
      float4 qm = *(float4*)&Qms[r][c];
      float4 km = *(float4*)&Kms[jj][c];
      s = fmaf(q.x, k.x, s);
      s = fmaf(q.y, k.y, s);
      s = fmaf(q.z, k.z, s);
      s = fmaf(q.w, k.w, s);
      s = fmaf(qm.x, km.x, s);
      s = fmaf(qm.y, km.y, s);
      s = fmaf(qm.z, km.z, s);
      s = fmaf(qm.w, km.w, s);
    }
    P[r * PS + jt + jj] = s * SCALEF;
  }
  __syncthreads();

  // ---- softmax over each of the 16 rows (2048 entries) ----
  const int seg = t & 15;
  {
    float m = -1e30f;
    const int base = r * PS + seg;  // stride-16 to dodge bank conflicts
    for (int i = 0; i < 128; ++i) m = fmaxf(m, P[base + i * 16]);
    red[t] = m;
  }
  __syncthreads();
  if (seg == 0) {
    float m = -1e30f;
    for (int k2 = 0; k2 < 16; ++k2) m = fmaxf(m, red[(r << 4) + k2]);
    rowmax[r] = m;
  }
  __syncthreads();
  {
    const float m = rowmax[r];
    float ssum = 0.f;
    const int base = r * PS + seg;
    for (int i = 0; i < 128; ++i) {
      float p = __expf(P[base + i * 16] - m);
      P[base + i * 16] = p;
      ssum += p;
    }
    red[t] = ssum;
  }
  __syncthreads();
  if (seg == 0) {
    float ssum = 0.f;
    for (int k2 = 0; k2 < 16; ++k2) ssum += red[(r << 4) + k2];
    rowinv[r] = 1.0f / ssum;
  }
  __syncthreads();

  // ---- write normalized attn (coalesced, one row at a time) ----
  for (int rr = 0; rr < 16; ++rr) {
    const float inv = rowinv[rr];
    const size_t base =
        (size_t)bh * NSEQ * NSEQ + (size_t)(qt * 16 + rr) * NSEQ;
    for (int idx = t; idx < NSEQ; idx += 256)
      attnO[base + idx] = P[rr * PS + idx] * inv;
  }

  // ---- PV: O1[r][64] += p_j * V[j][:], V read direct from global (L2) ----
  float4 acc = {0.f, 0.f, 0.f, 0.f};
  for (int j = 0; j < NSEQ; j += 4) {
    float4 pv = *(float4*)&P[r * PS + j];
    const float* vb = &V[(size_t)(b * NSEQ + j) * DIMW + hoff + d4];
    float4 v0 = *(const float4*)vb;
    float4 v1 = *(const float4*)(vb + DIMW);
    float4 v2 = *(const float4*)(vb + 2 * DIMW);
    float4 v3 = *(const float4*)(vb + 3 * DIMW);
    acc.x = fmaf(pv.x, v0.x, acc.x); acc.y = fmaf(pv.x, v0.y, acc.y);
    acc.z = fmaf(pv.x, v0.z, acc.z); acc.w = fmaf(pv.x, v0.w, acc.w);
    acc.x = fmaf(pv.y, v1.x, acc.x); acc.y = fmaf(pv.y, v1.y, acc.y);
    acc.z = fmaf(pv.y, v1.z, acc.z); acc.w = fmaf(pv.y, v1.w, acc.w);
    acc.x = fmaf(pv.z, v2.x, acc.x); acc.y = fmaf(pv.z, v2.y, acc.y);
    acc.z = fmaf(pv.z, v2.z, acc.z); acc.w = fmaf(pv.z, v2.w, acc.w);
    acc.x = fmaf(pv.w, v3.x, acc.x); acc.y = fmaf(pv.w, v3.y, acc.y);
    acc.z = fmaf(pv.w, v3.z, acc.z); acc.w = fmaf(pv.w, v3.w, acc.w);
  }
  {
    const float inv = rowinv[r];
    const size_t g = (size_t)(b * NSEQ + qt * 16 + r) * DIMW + hoff + d4;
    float4 o = {acc.x * inv, acc.y * inv, acc.z * inv, acc.w * inv};
    *(float4*)&O1[g] = o;
  }
}

// ---------------------------------------------------------------------------
extern "C" void kernel_launch(void* const* d_in, const int* in_sizes, int n_in,
                              void* d_out, int out_size, void* d_ws,
                              size_t ws_size, hipStream_t stream) {
  const float* x = (const float*)d_in[0];
  const float* met = (const float*)d_in[1];
  const float* yz = (const float*)d_in[2];
  const float* Wq = (const float*)d_in[3];
  const float* Wk = (const float*)d_in[4];
  const float* Wv = (const float*)d_in[5];
  const float* Wo = (const float*)d_in[6];
  const float* bo = (const float*)d_in[7];

  const size_t MROWS = (size_t)NB * NSEQ;  // 8192
  float* ws = (float*)d_ws;
  float* Q = ws;
  float* K = Q + MROWS * DIMW;
  float* V = K + MROWS * DIMW;
  float* Qm = V + MROWS * DIMW;
  float* Km = Qm + MROWS * DIMW;
  float* O1 = Km + MROWS * DIMW;

  float* outp = (float*)d_out;                       // (4,2048,512)
  float* attnO = outp + MROWS * DIMW;                // (32,2048,2048)

  dim3 gg(MROWS / 64, DIMW / 64);
  gemm512_f32<<<gg, 256, 0, stream>>>(x, Wq, Q, nullptr);
  gemm512_f32<<<gg, 256, 0, stream>>>(yz, Wk, K, nullptr);
  gemm512_f32<<<gg, 256, 0, stream>>>(yz, Wv, V, nullptr);
  gemm512_f32<<<gg, 256, 0, stream>>>(met, Wq, Qm, nullptr);
  gemm512_f32<<<gg, 256, 0, stream>>>(met, Wk, Km, nullptr);

  attn_f32<<<dim3(NSEQ / 16, NB * HEADS), 256, 0, stream>>>(Q, K, V, Qm, Km,
                                                            attnO, O1);

  gemm512_f32<<<gg, 256, 0, stream>>>(O1, Wo, outp, bo);
}